// Round 10
// baseline (226.964 us; speedup 1.0000x reference)
//
#include <hip/hip_runtime.h>
#include <math.h>

// Problem constants (setup_inputs: encodings [8192,64] f32, categorical [8192,25] f32, k=15)
#define Bsz    8192
#define Dd     64
#define NC     25
#define RT     32            // i-rows per block (TWO 16-row i-groups: halves L2 j-traffic)
#define KCAP   16            // >= k+1 (k clamped to 15)
#define EPSf   1e-5f
#define JMASK  2097151       // enc2 is exactly 2 MB; ring offsets wrap mod 2 MB
#define SENT   0x7FFFFFFF    // signed-compare sentinel (+max)

typedef short  short8  __attribute__((ext_vector_type(8)));
typedef float  floatx4 __attribute__((ext_vector_type(4)));

// Fragment-native layout: per 16-row group (4096 B):
//   [hi k0..31 : 1024B][hi k32..63 : 1024B][lo k0..31 : 1024B][lo k32..63 : 1024B]
// within a 1 KB chunk, lane l = quad*16 + c15 owns bytes l*16..l*16+15
// = row (group*16 + c15), elems k = quad*8 + khalf*32 .. +7.
// A wave's operand load = ONE coalesced global_load_dwordx4 (1 KB).
//
// Keys are SIGNED ints (R5/R6-verified bit-identical): float bits of d2, low 5
// bits replaced by label. No fmax clamp: only the self-distance can go
// negative and as a signed key it still sorts FIRST (same rank as the old
// clamped +0 key), so the kept neighbor multiset is unchanged.

__device__ inline unsigned short f2bf(float x) {           // RNE f32 -> bf16 bits
    unsigned u = __float_as_uint(x);
    u += 0x7FFFu + ((u >> 16) & 1u);
    return (unsigned short)(u >> 16);
}
__device__ inline float bf2f(unsigned short h) { return __uint_as_float(((unsigned)h) << 16); }

// Batcher odd-even mergesort, 16 regs ascending (signed). 63 CAS. (R1/R5-verified.)
__device__ inline void oesort16(int* a) {
    #pragma unroll
    for (int p = 1; p < 16; p <<= 1) {
        #pragma unroll
        for (int k = p; k >= 1; k >>= 1) {
            #pragma unroll
            for (int j = (k & (p - 1)); j + k < 16; j += 2 * k) {
                #pragma unroll
                for (int i = 0; i < k; ++i) {
                    if (i + j + k < 16 &&
                        ((i + j) / (2 * p)) == ((i + j + k) / (2 * p))) {
                        int x = a[i + j], y = a[i + j + k];
                        a[i + j]     = (x < y) ? x : y;
                        a[i + j + k] = (x < y) ? y : x;
                    }
                }
            }
        }
    }
}
__device__ inline void bclean16(int* t) {   // clean bitonic 16-seq to ascending
    #pragma unroll
    for (int j = 8; j > 0; j >>= 1)
        #pragma unroll
        for (int i = 0; i < 16; ++i) {
            int l = i ^ j;
            if (l > i) {
                int x = t[i], y = t[l];
                t[i] = (x < y) ? x : y;
                t[l] = (x < y) ? y : x;
            }
        }
}
// keep-low-16 merge of two sorted-asc 16-lists: ls = lowest16(ls ∪ b), sorted asc
__device__ inline void bmerge16(int* ls, const int* b) {
    int t[16];
    #pragma unroll
    for (int i = 0; i < 16; ++i) { int x = ls[i], y = b[15 - i]; t[i] = (x < y) ? x : y; }
    bclean16(t);
    #pragma unroll
    for (int i = 0; i < 16; ++i) ls[i] = t[i];
}
__device__ inline void bmerge16_shfl(int* ls, int mask) {   // partner via shfl_xor
    int t[16];
    #pragma unroll
    for (int i = 0; i < 16; ++i) {
        int pv = __shfl_xor(ls[15 - i], mask);
        int x = ls[i];
        t[i] = (x < pv) ? x : pv;
    }
    bclean16(t);
    #pragma unroll
    for (int i = 0; i < 16; ++i) ls[i] = t[i];
}

// One 16-j-row tile held fully in registers (4x short8 + uint4 = 20 VGPR).
struct TileR { short8 a0, a1, a2, a3; uint4 sv; };

__device__ __attribute__((always_inline)) inline void tile_load(
    TileR& T, const char* __restrict__ enc2, const unsigned* __restrict__ slab,
    int soff, int lane16, int quad4)
{
    const char* base = enc2 + soff + lane16;
    T.a0 = *(const short8*)(base);
    T.a1 = *(const short8*)(base + 1024);
    T.a2 = *(const short8*)(base + 2048);
    T.a3 = *(const short8*)(base + 3072);
    T.sv = *(const uint4*)(slab + (soff >> 8) + quad4);
}

// One j-tile vs TWO i-groups: 12 MFMAs as two interleaved 6-chains (ILP),
// pack 4+4 candidates. Per-acc accumulation order identical to the verified
// kernels (a0*bh0, a0*bl0, a2*bh0, a1*bh1, a1*bl1, a3*bh1); d2 assembled as
// ((sqi + sqj) + acc) exactly as before -> bit-identical keys.
__device__ __attribute__((always_inline)) inline void tile_mfma2(
    const TileR& T,
    const short8* bh0, const short8* bl0, const short8* bh1, const short8* bl1,
    float sqi0, float sqi1, int* c0, int* c1)
{
    floatx4 p = (floatx4){0.f, 0.f, 0.f, 0.f};
    floatx4 q = (floatx4){0.f, 0.f, 0.f, 0.f};
    p = __builtin_amdgcn_mfma_f32_16x16x32_bf16(T.a0, bh0[0], p, 0, 0, 0);
    q = __builtin_amdgcn_mfma_f32_16x16x32_bf16(T.a0, bh1[0], q, 0, 0, 0);
    p = __builtin_amdgcn_mfma_f32_16x16x32_bf16(T.a0, bl0[0], p, 0, 0, 0);
    q = __builtin_amdgcn_mfma_f32_16x16x32_bf16(T.a0, bl1[0], q, 0, 0, 0);
    p = __builtin_amdgcn_mfma_f32_16x16x32_bf16(T.a2, bh0[0], p, 0, 0, 0);
    q = __builtin_amdgcn_mfma_f32_16x16x32_bf16(T.a2, bh1[0], q, 0, 0, 0);
    p = __builtin_amdgcn_mfma_f32_16x16x32_bf16(T.a1, bh0[1], p, 0, 0, 0);
    q = __builtin_amdgcn_mfma_f32_16x16x32_bf16(T.a1, bh1[1], q, 0, 0, 0);
    p = __builtin_amdgcn_mfma_f32_16x16x32_bf16(T.a1, bl0[1], p, 0, 0, 0);
    q = __builtin_amdgcn_mfma_f32_16x16x32_bf16(T.a1, bl1[1], q, 0, 0, 0);
    p = __builtin_amdgcn_mfma_f32_16x16x32_bf16(T.a3, bh0[1], p, 0, 0, 0);
    q = __builtin_amdgcn_mfma_f32_16x16x32_bf16(T.a3, bh1[1], q, 0, 0, 0);

    const unsigned s4[4] = {T.sv.x, T.sv.y, T.sv.z, T.sv.w};
    #pragma unroll
    for (int r = 0; r < 4; ++r) {
        const unsigned sqb = s4[r] & ~31u, lb = s4[r] & 31u;   // shared by both i-groups
        float d0 = sqi0 + __uint_as_float(sqb) + p[r];
        c0[r] = (int)((__float_as_uint(d0) & ~31u) | lb);       // v_and_or_b32
        float d1 = sqi1 + __uint_as_float(sqb) + q[r];
        c1[r] = (int)((__float_as_uint(d1) & ~31u) | lb);
    }
}

// Output layout (f32, flat): [0..524287] encodings | [524288..532479] nbr entropy |
// [532480] cluster entropy | [532481] n_populated | [532482..540673] max_groups
//
// Workspace: slab u32[8192] @0 (bits(sq)&~31|label) | enc1 @32768 (2 MB, grouped frags of e)
//   enc2 @2129920 (2 MB, grouped frags of -2e). Ring offsets wrap mod 2 MB; all
//   tile reads stay inside enc2 (wrapped final refills re-read valid tiles, unused).
//
// R8/R9 lesson: __launch_bounds__'s 2nd arg only sets MIN waves/EU (a register
// CEILING) — the allocator's default heuristic still targeted 8 waves/EU
// (64-reg budget) and chose to SPILL the ~96-reg live set rather than lower
// occupancy (VGPR=64, WRITE_SIZE=382MB, twice). The pinning knob is
// amdgpu_waves_per_eu(min,MAX): max=4 forbids the 8-wave target, freeing the
// allocator to use up to 128 VGPRs. Logic is R8/R9-verified (both passed).

__global__ __launch_bounds__(256) void pre_kernel(
    const float* __restrict__ enc, const float* __restrict__ cat,
    unsigned int* __restrict__ slab,
    char* __restrict__ enc1, char* __restrict__ enc2,
    float* __restrict__ out_max, float* __restrict__ out_enc)
{
    const int gid = blockIdx.x * 256 + threadIdx.x;   // 1024 x 256 = 262144
    const int p = gid >> 5, pr = gid & 31;            // 32 threads/row, dims 2pr..2pr+1

    // single enc read serves passthrough copy and conversion (coalesced float2)
    float2 ev = ((const float2*)enc)[gid];
    ((float2*)out_enc)[gid] = ev;

    float s = ev.x * ev.x + ev.y * ev.y;
    #pragma unroll
    for (int m = 1; m < 32; m <<= 1) s += __shfl_xor(s, m, 32);   // row ssq

    // fragment-native address for dims d0 = 2pr, 2pr+1 (same 16B piece: d0 even)
    {
        const int g = p >> 4, c15p = p & 15;
        const int d0 = 2 * pr, kh = d0 >> 5, q = (d0 >> 3) & 3, e0 = d0 & 7;
        const int base = g * 4096 + kh * 1024 + (q * 16 + c15p) * 16 + e0 * 2;
        unsigned short ha = f2bf(ev.x), hb = f2bf(ev.y);
        unsigned short la = f2bf(ev.x - bf2f(ha)), lb = f2bf(ev.y - bf2f(hb));
        *(unsigned*)(enc1 + base)        = (unsigned)ha | ((unsigned)hb << 16);
        *(unsigned*)(enc1 + base + 2048) = (unsigned)la | ((unsigned)lb << 16);
        float y0 = -2.f * ev.x, y1 = -2.f * ev.y;
        unsigned short hc = f2bf(y0), hd = f2bf(y1);
        unsigned short lc = f2bf(y0 - bf2f(hc)), ld = f2bf(y1 - bf2f(hd));
        *(unsigned*)(enc2 + base)        = (unsigned)hc | ((unsigned)hd << 16);
        *(unsigned*)(enc2 + base + 2048) = (unsigned)lc | ((unsigned)ld << 16);
    }
    // categorical argmax across 32 lanes (first-max: ties -> min index; cat >= 0 so -1 sentinel safe)
    float cv = (pr < NC) ? cat[p * NC + pr] : -1.f;
    int ci = pr;
    #pragma unroll
    for (int m = 1; m < 32; m <<= 1) {
        float ov = __shfl_xor(cv, m, 32);
        int   oi = __shfl_xor(ci, m, 32);
        if (ov > cv || (ov == cv && oi < ci)) { cv = ov; ci = oi; }
    }
    if (pr == 0) {
        out_max[p] = cv;
        slab[p] = (__float_as_uint(s) & ~31u) | (unsigned)ci;  // sq trunc 2^-18 rel, harmless
    }
}

// Grid 256 x 1024 threads (16 waves): one block per 32 i-rows, 1 block/CU ->
// 4 waves/SIMD, register budget pinned to 128 via waves_per_eu(4,4).
// Rationale: at RT=32 the L2 read rate is 9.1 TB/s (below the ~15-20 TB/s wall
// that nulled R3's extra waves at RT=16); the 26% no-issue gap is wave-local
// dependency stall at 2 waves/SIMD. Doubling waves/SIMD at UNCHANGED block
// count keeps the per-block 2 MB j-stream (L2 traffic halved vs RT=16) while
// filling issue holes. Wave wv owns j-groups g ≡ wv (mod 16): tiles n=0..31
// at wvoff + n*65536; pipeline pair P = tiles (2P, 2P+1), R6-verified 4-phase
// ping-pong + sched_barrier, 8 iterations.
__global__ __attribute__((amdgpu_flat_work_group_size(1024, 1024),
                          amdgpu_waves_per_eu(4, 4)))
void main_kernel(
    const char* __restrict__ enc1, const char* __restrict__ enc2,
    const unsigned int* __restrict__ slab, const int* __restrict__ kptr,
    float* __restrict__ out_ent, float* __restrict__ out_glob)
{
    __shared__ int wl[16 * 32 * 17];   // 34816 B epilogue merge area (16 waves x 32 rows)
    __shared__ int cnt[32];

    const int tid  = threadIdx.x, bid = blockIdx.x;
    const int wv   = tid >> 6, lane = tid & 63;
    const int quad = (tid >> 4) & 3, c15 = tid & 15;
    const int rowbase = bid * RT;
    const int lane16 = lane * 16, quad4 = quad * 4;

    // i-fragments for BOTH i-groups (L1 broadcast across waves), hoisted
    short8 bh0[2], bl0[2], bh1[2], bl1[2];
    {
        const char* ib = enc1 + (size_t)bid * 8192 + lane16;
        bh0[0] = *(const short8*)(ib);
        bh0[1] = *(const short8*)(ib + 1024);
        bl0[0] = *(const short8*)(ib + 2048);
        bl0[1] = *(const short8*)(ib + 3072);
        bh1[0] = *(const short8*)(ib + 4096);
        bh1[1] = *(const short8*)(ib + 5120);
        bl1[0] = *(const short8*)(ib + 6144);
        bl1[1] = *(const short8*)(ib + 7168);
    }
    const float sqi0 = __uint_as_float(slab[rowbase + c15] & ~31u);
    const float sqi1 = __uint_as_float(slab[rowbase + 16 + c15] & ~31u);

    int ls0[KCAP], ls1[KCAP];   // per-thread sorted-ascending top-16 keys, per i-group
    #pragma unroll
    for (int q = 0; q < KCAP; ++q) { ls0[q] = SENT; ls1[q] = SENT; }

    const int wvoff = wv * 4096;

    TileR A0, A1, B0, B1;
    // prologue: pair 0 (tiles 0,1) into A buffers
    tile_load(A0, enc2, slab, wvoff,          lane16, quad4);
    tile_load(A1, enc2, slab, wvoff + 65536,  lane16, quad4);

    #pragma unroll 1
    for (int p = 0; p < 16; p += 2) {   // 8 iterations x 4 tiles = 32 tiles/wave
        int c0[16], c1[16];
        // phase 1: prefetch pair p+1 tile A -> B0; compute A0 vs both i-groups
        {
            const int o = (wvoff + (p + 1) * 131072) & JMASK;
            tile_load(B0, enc2, slab, o, lane16, quad4);
        }
        __builtin_amdgcn_sched_barrier(0);
        tile_mfma2(A0, bh0, bl0, bh1, bl1, sqi0, sqi1, c0, c1);
        // phase 2: prefetch pair p+1 tile B -> B1; compute A1
        {
            const int o = ((wvoff + (p + 1) * 131072) & JMASK) + 65536;
            tile_load(B1, enc2, slab, o, lane16, quad4);
        }
        __builtin_amdgcn_sched_barrier(0);
        tile_mfma2(A1, bh0, bl0, bh1, bl1, sqi0, sqi1, c0 + 4, c1 + 4);
        // phase 3: refill A0 with pair p+2 tile A; compute B0
        {
            const int o = (wvoff + (p + 2) * 131072) & JMASK;   // p=14 wraps to pair 0, unused
            tile_load(A0, enc2, slab, o, lane16, quad4);
        }
        __builtin_amdgcn_sched_barrier(0);
        tile_mfma2(B0, bh0, bl0, bh1, bl1, sqi0, sqi1, c0 + 8, c1 + 8);
        // phase 4: refill A1 with pair p+2 tile B; compute B1
        {
            const int o = ((wvoff + (p + 2) * 131072) & JMASK) + 65536;
            tile_load(A1, enc2, slab, o, lane16, quad4);
        }
        __builtin_amdgcn_sched_barrier(0);
        tile_mfma2(B1, bh0, bl0, bh1, bl1, sqi0, sqi1, c0 + 12, c1 + 12);
        // branchless selection on both 16-candidate batches (hides A-refill flight)
        oesort16(c0);
        bmerge16(ls0, c0);
        oesort16(c1);
        bmerge16(ls1, c1);
    }

    // ---- block 0: global cluster entropy from slab labels (block-uniform branch) ----
    if (bid == 0) {
        if (tid < 32) cnt[tid] = 0;
        __syncthreads();
        for (int i = tid; i < Bsz; i += 1024) atomicAdd(&cnt[slab[i] & 31u], 1);
        __syncthreads();
        if (tid == 0) {
            float gent = 0.f, npop = 0.f;
            for (int i = 0; i < NC; ++i) {
                int g = cnt[i];
                if (g > 0) {
                    npop += 1.f;
                    float gb = (float)g / (float)Bsz;
                    gent -= gb * logf(gb + EPSf);
                }
            }
            out_glob[0] = gent;
            out_glob[1] = npop;
        }
        __syncthreads();
    }

    // ---- epilogue: merge 4 quads (shfl) per i-group, then 16 waves (LDS), per i-row ----
    bmerge16_shfl(ls0, 16);   // quad ^ 1
    bmerge16_shfl(ls0, 32);   // quad ^ 2 -> wave-level sorted top-16 (rows 0..15)
    bmerge16_shfl(ls1, 16);
    bmerge16_shfl(ls1, 32);   // rows 16..31
    if (quad == 0) {
        #pragma unroll
        for (int q = 0; q < KCAP; ++q) wl[(wv * 32 + c15) * 17 + q]      = ls0[q];
        #pragma unroll
        for (int q = 0; q < KCAP; ++q) wl[(wv * 32 + 16 + c15) * 17 + q] = ls1[q];
    }
    __syncthreads();
    if (wv < 2) {   // 128 threads: 32 rows x 4 subs, merge 16 wave-lists -> entropy
        const int row = tid >> 2, sub = tid & 3;   // row 0..31, sub-groups stay in-wave
        int A[16], Bv[16];
        #pragma unroll
        for (int i = 0; i < 16; ++i) A[i]  = wl[((4 * sub)     * 32 + row) * 17 + i];
        #pragma unroll
        for (int i = 0; i < 16; ++i) Bv[i] = wl[((4 * sub + 1) * 32 + row) * 17 + i];
        bmerge16(A, Bv);
        #pragma unroll
        for (int i = 0; i < 16; ++i) Bv[i] = wl[((4 * sub + 2) * 32 + row) * 17 + i];
        bmerge16(A, Bv);
        #pragma unroll
        for (int i = 0; i < 16; ++i) Bv[i] = wl[((4 * sub + 3) * 32 + row) * 17 + i];
        bmerge16(A, Bv);
        bmerge16_shfl(A, 1);   // sub ^ 1
        bmerge16_shfl(A, 2);   // sub ^ 2 -> row's global sorted top-16 in all subs

        int kk = kptr[0];
        if (kk > Bsz / 4) kk = Bsz / 4;
        if (kk > KCAP - 1) kk = KCAP - 1;

        int kth = A[15];
        #pragma unroll
        for (int q = 0; q < 16; ++q) if (q == kk) kth = A[q];
        int nn = 0;
        #pragma unroll
        for (int t = 0; t < 15; ++t) nn += (t < kk && A[t] < kth) ? 1 : 0;  // strict <, sorted prefix

        float inv = 1.f / (float)((nn > 0) ? nn : 1);
        float part = 0.f;
        #pragma unroll
        for (int a4 = 0; a4 < 4; ++a4) {
            int a = sub + 4 * a4;
            if (a < nn) {
                int la = A[a] & 31;
                int c = 0;
                #pragma unroll
                for (int b = 0; b < 15; ++b) c += (b < nn && (A[b] & 31) == la) ? 1 : 0;
                part -= inv * logf((float)c * inv + EPSf);
            }
        }
        part += __shfl_xor(part, 1);
        part += __shfl_xor(part, 2);
        if (sub == 0) out_ent[rowbase + row] = part;
    }
}

extern "C" void kernel_launch(void* const* d_in, const int* in_sizes, int n_in,
                              void* d_out, int out_size, void* d_ws, size_t ws_size,
                              hipStream_t stream)
{
    const float* enc  = (const float*)d_in[0];
    const float* cat  = (const float*)d_in[1];
    const int*   kptr = (const int*)d_in[2];
    float* out = (float*)d_out;

    unsigned int* slab = (unsigned int*)d_ws;
    char*         enc1 = (char*)d_ws + 32768;
    char*         enc2 = (char*)d_ws + 2129920;

    float* out_enc  = out;
    float* out_ent  = out + Bsz * Dd;                 // 524288
    float* out_glob = out + Bsz * Dd + Bsz;           // 532480 (entropy, n_populated)
    float* out_max  = out + Bsz * Dd + Bsz + 2;       // 532482

    pre_kernel<<<1024, 256, 0, stream>>>(enc, cat, slab, enc1, enc2, out_max, out_enc);
    main_kernel<<<Bsz / RT, 1024, 0, stream>>>(enc1, enc2, slab, kptr, out_ent, out_glob);
}

// Round 11
// 115.177 us; speedup vs baseline: 1.9706x; 1.9706x over previous
//
#include <hip/hip_runtime.h>
#include <math.h>

// Problem constants (setup_inputs: encodings [8192,64] f32, categorical [8192,25] f32, k=15)
#define Bsz    8192
#define Dd     64
#define NC     25
#define RT     32            // i-rows per block (TWO 16-row i-groups: halves L2 j-traffic)
#define KCAP   16            // >= k+1 (k clamped to 15)
#define EPSf   1e-5f
#define JMASK  2097151       // enc2 is exactly 2 MB; ring offsets wrap mod 2 MB
#define SENT   0x7FFFFFFF    // signed-compare sentinel (+max)

typedef short  short8  __attribute__((ext_vector_type(8)));
typedef float  floatx4 __attribute__((ext_vector_type(4)));

// Fragment-native layout: per 16-row group (4096 B):
//   [hi k0..31 : 1024B][hi k32..63 : 1024B][lo k0..31 : 1024B][lo k32..63 : 1024B]
// within a 1 KB chunk, lane l = quad*16 + c15 owns bytes l*16..l*16+15
// = row (group*16 + c15), elems k = quad*8 + khalf*32 .. +7.
// A wave's operand load = ONE coalesced global_load_dwordx4 (1 KB).
//
// Keys are SIGNED ints (R5/R6-verified bit-identical): float bits of d2, low 5
// bits replaced by label. No fmax clamp: only the self-distance can go
// negative and as a signed key it still sorts FIRST, so the kept neighbor
// multiset is unchanged.
//
// R8-R10 lesson (closed path): 1024-thread blocks always spill — the
// allocator pins a 64-reg budget (8 waves/EU target) regardless of
// __launch_bounds__(,4) or amdgpu_waves_per_eu(4,4). Geometry stays R6:
// grid 256 x 512 threads, VGPR ~92, zero spill.
//
// R11 change: software-pipeline the SELECTION across phases. R6 serialized
// [loads+MFMA] then [sort] per trip (sched_barriers + program order), so the
// MFMA pipe idled during the VALU-chain-bound sorts and vice versa (VALUBusy
// pinned ~56% at ALL occupancies R0..R6). Now candidates fill fixed 8-slot
// buffers (a* in phases 1-2, b* in phases 3-4) and each batch's sort is
// placed ONE PHASE LATER, inside the next MFMA region: the 12 independent
// MFMAs fill the sort chain's dependency-stall slots. Exact top-16 multiset
// is batch-size-invariant -> bit-identical output (8-batch path R3-verified).

__device__ inline unsigned short f2bf(float x) {           // RNE f32 -> bf16 bits
    unsigned u = __float_as_uint(x);
    u += 0x7FFFu + ((u >> 16) & 1u);
    return (unsigned short)(u >> 16);
}
__device__ inline float bf2f(unsigned short h) { return __uint_as_float(((unsigned)h) << 16); }

// Batcher odd-even mergesort, 8 regs ascending (signed). 19 CAS. (R3-verified generator.)
__device__ inline void oesort8(int* a) {
    #pragma unroll
    for (int p = 1; p < 8; p <<= 1) {
        #pragma unroll
        for (int k = p; k >= 1; k >>= 1) {
            #pragma unroll
            for (int j = (k & (p - 1)); j + k < 8; j += 2 * k) {
                #pragma unroll
                for (int i = 0; i < k; ++i) {
                    if (i + j + k < 8 &&
                        ((i + j) / (2 * p)) == ((i + j + k) / (2 * p))) {
                        int x = a[i + j], y = a[i + j + k];
                        a[i + j]     = (x < y) ? x : y;
                        a[i + j + k] = (x < y) ? y : x;
                    }
                }
            }
        }
    }
}
__device__ inline void bclean16(int* t) {   // clean bitonic 16-seq to ascending
    #pragma unroll
    for (int j = 8; j > 0; j >>= 1)
        #pragma unroll
        for (int i = 0; i < 16; ++i) {
            int l = i ^ j;
            if (l > i) {
                int x = t[i], y = t[l];
                t[i] = (x < y) ? x : y;
                t[l] = (x < y) ? y : x;
            }
        }
}
// keep-low-16 merge of sorted-asc 16-list with sorted-asc 8-list (virtual +inf pad).
// (R3-HW-verified pattern; signed variant.)
__device__ inline void bmerge16_8(int* ls, const int* c) {
    int t[16];
    #pragma unroll
    for (int i = 0; i < 8; ++i) t[i] = ls[i];
    #pragma unroll
    for (int m = 0; m < 8; ++m) { int x = ls[8 + m], y = c[7 - m]; t[8 + m] = (x < y) ? x : y; }
    bclean16(t);
    #pragma unroll
    for (int i = 0; i < 16; ++i) ls[i] = t[i];
}
// keep-low-16 merge of two sorted-asc 16-lists (epilogue use)
__device__ inline void bmerge16(int* ls, const int* b) {
    int t[16];
    #pragma unroll
    for (int i = 0; i < 16; ++i) { int x = ls[i], y = b[15 - i]; t[i] = (x < y) ? x : y; }
    bclean16(t);
    #pragma unroll
    for (int i = 0; i < 16; ++i) ls[i] = t[i];
}
__device__ inline void bmerge16_shfl(int* ls, int mask) {   // partner via shfl_xor
    int t[16];
    #pragma unroll
    for (int i = 0; i < 16; ++i) {
        int pv = __shfl_xor(ls[15 - i], mask);
        int x = ls[i];
        t[i] = (x < pv) ? x : pv;
    }
    bclean16(t);
    #pragma unroll
    for (int i = 0; i < 16; ++i) ls[i] = t[i];
}

// One 16-j-row tile held fully in registers (4x short8 + uint4 = 20 VGPR).
struct TileR { short8 a0, a1, a2, a3; uint4 sv; };

__device__ __attribute__((always_inline)) inline void tile_load(
    TileR& T, const char* __restrict__ enc2, const unsigned* __restrict__ slab,
    int soff, int lane16, int quad4)
{
    const char* base = enc2 + soff + lane16;
    T.a0 = *(const short8*)(base);
    T.a1 = *(const short8*)(base + 1024);
    T.a2 = *(const short8*)(base + 2048);
    T.a3 = *(const short8*)(base + 3072);
    T.sv = *(const uint4*)(slab + (soff >> 8) + quad4);
}

// One j-tile vs TWO i-groups: 12 MFMAs as two interleaved 6-chains (ILP),
// pack 4+4 candidates. Per-acc accumulation order identical to the verified
// kernels (a0*bh0, a0*bl0, a2*bh0, a1*bh1, a1*bl1, a3*bh1); d2 assembled as
// ((sqi + sqj) + acc) exactly as before -> bit-identical keys.
__device__ __attribute__((always_inline)) inline void tile_mfma2(
    const TileR& T,
    const short8* bh0, const short8* bl0, const short8* bh1, const short8* bl1,
    float sqi0, float sqi1, int* c0, int* c1)
{
    floatx4 p = (floatx4){0.f, 0.f, 0.f, 0.f};
    floatx4 q = (floatx4){0.f, 0.f, 0.f, 0.f};
    p = __builtin_amdgcn_mfma_f32_16x16x32_bf16(T.a0, bh0[0], p, 0, 0, 0);
    q = __builtin_amdgcn_mfma_f32_16x16x32_bf16(T.a0, bh1[0], q, 0, 0, 0);
    p = __builtin_amdgcn_mfma_f32_16x16x32_bf16(T.a0, bl0[0], p, 0, 0, 0);
    q = __builtin_amdgcn_mfma_f32_16x16x32_bf16(T.a0, bl1[0], q, 0, 0, 0);
    p = __builtin_amdgcn_mfma_f32_16x16x32_bf16(T.a2, bh0[0], p, 0, 0, 0);
    q = __builtin_amdgcn_mfma_f32_16x16x32_bf16(T.a2, bh1[0], q, 0, 0, 0);
    p = __builtin_amdgcn_mfma_f32_16x16x32_bf16(T.a1, bh0[1], p, 0, 0, 0);
    q = __builtin_amdgcn_mfma_f32_16x16x32_bf16(T.a1, bh1[1], q, 0, 0, 0);
    p = __builtin_amdgcn_mfma_f32_16x16x32_bf16(T.a1, bl0[1], p, 0, 0, 0);
    q = __builtin_amdgcn_mfma_f32_16x16x32_bf16(T.a1, bl1[1], q, 0, 0, 0);
    p = __builtin_amdgcn_mfma_f32_16x16x32_bf16(T.a3, bh0[1], p, 0, 0, 0);
    q = __builtin_amdgcn_mfma_f32_16x16x32_bf16(T.a3, bh1[1], q, 0, 0, 0);

    const unsigned s4[4] = {T.sv.x, T.sv.y, T.sv.z, T.sv.w};
    #pragma unroll
    for (int r = 0; r < 4; ++r) {
        const unsigned sqb = s4[r] & ~31u, lb = s4[r] & 31u;   // shared by both i-groups
        float d0 = sqi0 + __uint_as_float(sqb) + p[r];
        c0[r] = (int)((__float_as_uint(d0) & ~31u) | lb);       // v_and_or_b32
        float d1 = sqi1 + __uint_as_float(sqb) + q[r];
        c1[r] = (int)((__float_as_uint(d1) & ~31u) | lb);
    }
}

// Output layout (f32, flat): [0..524287] encodings | [524288..532479] nbr entropy |
// [532480] cluster entropy | [532481] n_populated | [532482..540673] max_groups
//
// Workspace: slab u32[8192] @0 (bits(sq)&~31|label) | enc1 @32768 (2 MB, grouped frags of e)
//   enc2 @2129920 (2 MB, grouped frags of -2e). Ring offsets wrap mod 2 MB; all
//   tile reads stay inside enc2 (wrapped final refills re-read valid tiles, unused).

__global__ __launch_bounds__(256) void pre_kernel(
    const float* __restrict__ enc, const float* __restrict__ cat,
    unsigned int* __restrict__ slab,
    char* __restrict__ enc1, char* __restrict__ enc2,
    float* __restrict__ out_max, float* __restrict__ out_enc)
{
    const int gid = blockIdx.x * 256 + threadIdx.x;   // 1024 x 256 = 262144
    const int p = gid >> 5, pr = gid & 31;            // 32 threads/row, dims 2pr..2pr+1

    // single enc read serves passthrough copy and conversion (coalesced float2)
    float2 ev = ((const float2*)enc)[gid];
    ((float2*)out_enc)[gid] = ev;

    float s = ev.x * ev.x + ev.y * ev.y;
    #pragma unroll
    for (int m = 1; m < 32; m <<= 1) s += __shfl_xor(s, m, 32);   // row ssq

    // fragment-native address for dims d0 = 2pr, 2pr+1 (same 16B piece: d0 even)
    {
        const int g = p >> 4, c15p = p & 15;
        const int d0 = 2 * pr, kh = d0 >> 5, q = (d0 >> 3) & 3, e0 = d0 & 7;
        const int base = g * 4096 + kh * 1024 + (q * 16 + c15p) * 16 + e0 * 2;
        unsigned short ha = f2bf(ev.x), hb = f2bf(ev.y);
        unsigned short la = f2bf(ev.x - bf2f(ha)), lb = f2bf(ev.y - bf2f(hb));
        *(unsigned*)(enc1 + base)        = (unsigned)ha | ((unsigned)hb << 16);
        *(unsigned*)(enc1 + base + 2048) = (unsigned)la | ((unsigned)lb << 16);
        float y0 = -2.f * ev.x, y1 = -2.f * ev.y;
        unsigned short hc = f2bf(y0), hd = f2bf(y1);
        unsigned short lc = f2bf(y0 - bf2f(hc)), ld = f2bf(y1 - bf2f(hd));
        *(unsigned*)(enc2 + base)        = (unsigned)hc | ((unsigned)hd << 16);
        *(unsigned*)(enc2 + base + 2048) = (unsigned)lc | ((unsigned)ld << 16);
    }
    // categorical argmax across 32 lanes (first-max: ties -> min index; cat >= 0 so -1 sentinel safe)
    float cv = (pr < NC) ? cat[p * NC + pr] : -1.f;
    int ci = pr;
    #pragma unroll
    for (int m = 1; m < 32; m <<= 1) {
        float ov = __shfl_xor(cv, m, 32);
        int   oi = __shfl_xor(ci, m, 32);
        if (ov > cv || (ov == cv && oi < ci)) { cv = ov; ci = oi; }
    }
    if (pr == 0) {
        out_max[p] = cv;
        slab[p] = (__float_as_uint(s) & ~31u) | (unsigned)ci;  // sq trunc 2^-18 rel, harmless
    }
}

// Grid 256 x 512 threads (8 waves), R6 geometry (best verified: 58us, no
// spill). Wave wv owns j-groups g ≡ wv (mod 8): tile n (n=0..63) at byte
// offset wvoff + n*32768. Trip u handles tiles 4u..4u+3 in 4 phases; loads
// prefetch 2 tiles ahead (R4-verified sched_barrier pinning). NEW: each
// 8-candidate batch's sort+merge executes one phase after readiness, inside
// the next MFMA region (see header comment).
__global__ __launch_bounds__(512) void main_kernel(
    const char* __restrict__ enc1, const char* __restrict__ enc2,
    const unsigned int* __restrict__ slab, const int* __restrict__ kptr,
    float* __restrict__ out_ent, float* __restrict__ out_glob)
{
    __shared__ int wl[8 * 32 * 17];   // 17408 B epilogue merge area (8 waves x 32 rows)
    __shared__ int cnt[32];

    const int tid  = threadIdx.x, bid = blockIdx.x;
    const int wv   = tid >> 6, lane = tid & 63;
    const int quad = (tid >> 4) & 3, c15 = tid & 15;
    const int rowbase = bid * RT;
    const int lane16 = lane * 16, quad4 = quad * 4;

    // i-fragments for BOTH i-groups (L1 broadcast across waves), hoisted
    short8 bh0[2], bl0[2], bh1[2], bl1[2];
    {
        const char* ib = enc1 + (size_t)bid * 8192 + lane16;
        bh0[0] = *(const short8*)(ib);
        bh0[1] = *(const short8*)(ib + 1024);
        bl0[0] = *(const short8*)(ib + 2048);
        bl0[1] = *(const short8*)(ib + 3072);
        bh1[0] = *(const short8*)(ib + 4096);
        bh1[1] = *(const short8*)(ib + 5120);
        bl1[0] = *(const short8*)(ib + 6144);
        bl1[1] = *(const short8*)(ib + 7168);
    }
    const float sqi0 = __uint_as_float(slab[rowbase + c15] & ~31u);
    const float sqi1 = __uint_as_float(slab[rowbase + 16 + c15] & ~31u);

    int ls0[KCAP], ls1[KCAP];   // per-thread sorted-ascending top-16 keys, per i-group
    #pragma unroll
    for (int q = 0; q < KCAP; ++q) { ls0[q] = SENT; ls1[q] = SENT; }

    const int wvoff = wv * 4096;

    // candidate chunk buffers with FIXED roles (no copies):
    //   a0/a1: i-group0/1 chunk from phases 1-2 of current trip
    //   b0/b1: i-group0/1 chunk from phases 3-4 (sorted in NEXT trip's ph1/2)
    int a0[8], a1[8], b0[8], b1[8];
    #pragma unroll
    for (int q = 0; q < 8; ++q) { b0[q] = SENT; b1[q] = SENT; }  // trip-0 ph1/2 sorts: exact no-op

    TileR A0, A1, B0, B1;
    tile_load(A0, enc2, slab, wvoff,          lane16, quad4);            // tile 0
    tile_load(A1, enc2, slab, wvoff + 32768,  lane16, quad4);            // tile 1

    #pragma unroll 1
    for (int u = 0; u < 16; ++u) {
        const int base = wvoff + u * 131072;   // tile 4u at base
        // phase 1: load tile 4u+2 -> B0 | mfma A0 -> a*[0:4) | sort prev b0 -> ls0
        tile_load(B0, enc2, slab, (base + 65536) & JMASK, lane16, quad4);
        __builtin_amdgcn_sched_barrier(0);
        tile_mfma2(A0, bh0, bl0, bh1, bl1, sqi0, sqi1, a0, a1);
        oesort8(b0);
        bmerge16_8(ls0, b0);
        // phase 2: load tile 4u+3 -> B1 | mfma A1 -> a*[4:8) | sort prev b1 -> ls1
        tile_load(B1, enc2, slab, (base + 98304) & JMASK, lane16, quad4);
        __builtin_amdgcn_sched_barrier(0);
        tile_mfma2(A1, bh0, bl0, bh1, bl1, sqi0, sqi1, a0 + 4, a1 + 4);
        oesort8(b1);
        bmerge16_8(ls1, b1);
        // phase 3: load tile 4u+4 -> A0 | mfma B0 -> b*[0:4) | sort a0 -> ls0
        tile_load(A0, enc2, slab, (base + 131072) & JMASK, lane16, quad4);
        __builtin_amdgcn_sched_barrier(0);
        tile_mfma2(B0, bh0, bl0, bh1, bl1, sqi0, sqi1, b0, b1);
        oesort8(a0);
        bmerge16_8(ls0, a0);
        // phase 4: load tile 4u+5 -> A1 | mfma B1 -> b*[4:8) | sort a1 -> ls1
        tile_load(A1, enc2, slab, (base + 163840) & JMASK, lane16, quad4);
        __builtin_amdgcn_sched_barrier(0);
        tile_mfma2(B1, bh0, bl0, bh1, bl1, sqi0, sqi1, b0 + 4, b1 + 4);
        oesort8(a1);
        bmerge16_8(ls1, a1);
    }
    // epilogue of the selection pipeline: final b0/b1 batches (tiles 62,63)
    oesort8(b0);
    bmerge16_8(ls0, b0);
    oesort8(b1);
    bmerge16_8(ls1, b1);

    // ---- block 0: global cluster entropy from slab labels (block-uniform branch) ----
    if (bid == 0) {
        if (tid < 32) cnt[tid] = 0;
        __syncthreads();
        for (int i = tid; i < Bsz; i += 512) atomicAdd(&cnt[slab[i] & 31u], 1);
        __syncthreads();
        if (tid == 0) {
            float gent = 0.f, npop = 0.f;
            for (int i = 0; i < NC; ++i) {
                int g = cnt[i];
                if (g > 0) {
                    npop += 1.f;
                    float gb = (float)g / (float)Bsz;
                    gent -= gb * logf(gb + EPSf);
                }
            }
            out_glob[0] = gent;
            out_glob[1] = npop;
        }
        __syncthreads();
    }

    // ---- epilogue: merge 4 quads (shfl) per i-group, then 8 waves (LDS), per i-row ----
    bmerge16_shfl(ls0, 16);   // quad ^ 1
    bmerge16_shfl(ls0, 32);   // quad ^ 2 -> wave-level sorted top-16 (rows 0..15)
    bmerge16_shfl(ls1, 16);
    bmerge16_shfl(ls1, 32);   // rows 16..31
    if (quad == 0) {
        #pragma unroll
        for (int q = 0; q < KCAP; ++q) wl[(wv * 32 + c15) * 17 + q]      = ls0[q];
        #pragma unroll
        for (int q = 0; q < KCAP; ++q) wl[(wv * 32 + 16 + c15) * 17 + q] = ls1[q];
    }
    __syncthreads();
    if (wv < 2) {   // 128 threads: 32 rows x 4 subs, merge 8 wave-lists -> entropy
        const int row = tid >> 2, sub = tid & 3;   // row 0..31, sub-groups stay in-wave
        int A[16], Bv[16];
        #pragma unroll
        for (int i = 0; i < 16; ++i) A[i]  = wl[((2 * sub)     * 32 + row) * 17 + i];
        #pragma unroll
        for (int i = 0; i < 16; ++i) Bv[i] = wl[((2 * sub + 1) * 32 + row) * 17 + i];
        bmerge16(A, Bv);
        bmerge16_shfl(A, 1);   // sub ^ 1
        bmerge16_shfl(A, 2);   // sub ^ 2 -> row's global sorted top-16 in all subs

        int kk = kptr[0];
        if (kk > Bsz / 4) kk = Bsz / 4;
        if (kk > KCAP - 1) kk = KCAP - 1;

        int kth = A[15];
        #pragma unroll
        for (int q = 0; q < 16; ++q) if (q == kk) kth = A[q];
        int nn = 0;
        #pragma unroll
        for (int t = 0; t < 15; ++t) nn += (t < kk && A[t] < kth) ? 1 : 0;  // strict <, sorted prefix

        float inv = 1.f / (float)((nn > 0) ? nn : 1);
        float part = 0.f;
        #pragma unroll
        for (int a4 = 0; a4 < 4; ++a4) {
            int a = sub + 4 * a4;
            if (a < nn) {
                int la = A[a] & 31;
                int c = 0;
                #pragma unroll
                for (int b = 0; b < 15; ++b) c += (b < nn && (A[b] & 31) == la) ? 1 : 0;
                part -= inv * logf((float)c * inv + EPSf);
            }
        }
        part += __shfl_xor(part, 1);
        part += __shfl_xor(part, 2);
        if (sub == 0) out_ent[rowbase + row] = part;
    }
}

extern "C" void kernel_launch(void* const* d_in, const int* in_sizes, int n_in,
                              void* d_out, int out_size, void* d_ws, size_t ws_size,
                              hipStream_t stream)
{
    const float* enc  = (const float*)d_in[0];
    const float* cat  = (const float*)d_in[1];
    const int*   kptr = (const int*)d_in[2];
    float* out = (float*)d_out;

    unsigned int* slab = (unsigned int*)d_ws;
    char*         enc1 = (char*)d_ws + 32768;
    char*         enc2 = (char*)d_ws + 2129920;

    float* out_enc  = out;
    float* out_ent  = out + Bsz * Dd;                 // 524288
    float* out_glob = out + Bsz * Dd + Bsz;           // 532480 (entropy, n_populated)
    float* out_max  = out + Bsz * Dd + Bsz + 2;       // 532482

    pre_kernel<<<1024, 256, 0, stream>>>(enc, cat, slab, enc1, enc2, out_max, out_enc);
    main_kernel<<<Bsz / RT, 512, 0, stream>>>(enc1, enc2, slab, kptr, out_ent, out_glob);
}

// Round 12
// 109.996 us; speedup vs baseline: 2.0634x; 1.0471x over previous
//
#include <hip/hip_runtime.h>
#include <math.h>

// Problem constants (setup_inputs: encodings [8192,64] f32, categorical [8192,25] f32, k=15)
#define Bsz    8192
#define Dd     64
#define NC     25
#define RT     32            // i-rows per block (TWO 16-row i-groups: halves L2 j-traffic)
#define KCAP   16            // >= k+1 (k clamped to 15)
#define EPSf   1e-5f
#define JMASK  2097151       // enc2 is exactly 2 MB; ring offsets wrap mod 2 MB
#define SENT   0x7FFFFFFF    // signed-compare sentinel (+max)

typedef short  short8  __attribute__((ext_vector_type(8)));
typedef float  floatx4 __attribute__((ext_vector_type(4)));

// Fragment-native layout: per 16-row group (4096 B):
//   [hi k0..31 : 1024B][hi k32..63 : 1024B][lo k0..31 : 1024B][lo k32..63 : 1024B]
// within a 1 KB chunk, lane l = quad*16 + c15 owns bytes l*16..l*16+15
// = row (group*16 + c15), elems k = quad*8 + khalf*32 .. +7.
// A wave's operand load = ONE coalesced global_load_dwordx4 (1 KB).
//
// Keys are SIGNED ints (R5/R6-verified bit-identical): float bits of d2, low 5
// bits replaced by label. No fmax clamp: only the self-distance can go
// negative and as a signed key it still sorts FIRST, so the kept neighbor
// multiset is unchanged.
//
// Session ledger (what is closed):
//  - 1024-thr blocks: allocator pins 64-reg budget, always spills (R8-R10).
//  - Occupancy 1.4..5.7 waves/SIMD: duration invariant (R0/R3/R6).
//  - Cooperative fusion: grid.sync costs ~45us on 8 XCDs (R7).
//  - Cross-block j-split: handshake collapse (R2).
//  - Sort batch 8 vs 16, cross-phase sort placement: null (R11).
//  - Threshold-filter selection: analyzed, EV~0 (256-cand/lane streams too
//    short to amortize bootstrap+rebuild fixed costs).
// R12 = R6 (best verified: main 58us, total 111.7us) + s_setprio around the
// MFMA+pack region. Main loop has NO barriers -> waves independent -> the
// regime where setprio measured +4-7% (attn, m191), not the null/negative
// lockstep-GEMM regime (m190).

__device__ inline unsigned short f2bf(float x) {           // RNE f32 -> bf16 bits
    unsigned u = __float_as_uint(x);
    u += 0x7FFFu + ((u >> 16) & 1u);
    return (unsigned short)(u >> 16);
}
__device__ inline float bf2f(unsigned short h) { return __uint_as_float(((unsigned)h) << 16); }

// Batcher odd-even mergesort, 16 regs ascending (signed). 63 CAS. (R1/R5-verified.)
__device__ inline void oesort16(int* a) {
    #pragma unroll
    for (int p = 1; p < 16; p <<= 1) {
        #pragma unroll
        for (int k = p; k >= 1; k >>= 1) {
            #pragma unroll
            for (int j = (k & (p - 1)); j + k < 16; j += 2 * k) {
                #pragma unroll
                for (int i = 0; i < k; ++i) {
                    if (i + j + k < 16 &&
                        ((i + j) / (2 * p)) == ((i + j + k) / (2 * p))) {
                        int x = a[i + j], y = a[i + j + k];
                        a[i + j]     = (x < y) ? x : y;
                        a[i + j + k] = (x < y) ? y : x;
                    }
                }
            }
        }
    }
}
__device__ inline void bclean16(int* t) {   // clean bitonic 16-seq to ascending
    #pragma unroll
    for (int j = 8; j > 0; j >>= 1)
        #pragma unroll
        for (int i = 0; i < 16; ++i) {
            int l = i ^ j;
            if (l > i) {
                int x = t[i], y = t[l];
                t[i] = (x < y) ? x : y;
                t[l] = (x < y) ? y : x;
            }
        }
}
// keep-low-16 merge of two sorted-asc 16-lists: ls = lowest16(ls ∪ b), sorted asc
__device__ inline void bmerge16(int* ls, const int* b) {
    int t[16];
    #pragma unroll
    for (int i = 0; i < 16; ++i) { int x = ls[i], y = b[15 - i]; t[i] = (x < y) ? x : y; }
    bclean16(t);
    #pragma unroll
    for (int i = 0; i < 16; ++i) ls[i] = t[i];
}
__device__ inline void bmerge16_shfl(int* ls, int mask) {   // partner via shfl_xor
    int t[16];
    #pragma unroll
    for (int i = 0; i < 16; ++i) {
        int pv = __shfl_xor(ls[15 - i], mask);
        int x = ls[i];
        t[i] = (x < pv) ? x : pv;
    }
    bclean16(t);
    #pragma unroll
    for (int i = 0; i < 16; ++i) ls[i] = t[i];
}

// One 16-j-row tile held fully in registers (4x short8 + uint4 = 20 VGPR).
struct TileR { short8 a0, a1, a2, a3; uint4 sv; };

__device__ __attribute__((always_inline)) inline void tile_load(
    TileR& T, const char* __restrict__ enc2, const unsigned* __restrict__ slab,
    int soff, int lane16, int quad4)
{
    const char* base = enc2 + soff + lane16;
    T.a0 = *(const short8*)(base);
    T.a1 = *(const short8*)(base + 1024);
    T.a2 = *(const short8*)(base + 2048);
    T.a3 = *(const short8*)(base + 3072);
    T.sv = *(const uint4*)(slab + (soff >> 8) + quad4);
}

// One j-tile vs TWO i-groups: 12 MFMAs as two interleaved 6-chains (ILP),
// pack 4+4 candidates. Per-acc accumulation order identical to the verified
// kernels (a0*bh0, a0*bl0, a2*bh0, a1*bh1, a1*bl1, a3*bh1); d2 assembled as
// ((sqi + sqj) + acc) exactly as before -> bit-identical keys.
__device__ __attribute__((always_inline)) inline void tile_mfma2(
    const TileR& T,
    const short8* bh0, const short8* bl0, const short8* bh1, const short8* bl1,
    float sqi0, float sqi1, int* c0, int* c1)
{
    floatx4 p = (floatx4){0.f, 0.f, 0.f, 0.f};
    floatx4 q = (floatx4){0.f, 0.f, 0.f, 0.f};
    p = __builtin_amdgcn_mfma_f32_16x16x32_bf16(T.a0, bh0[0], p, 0, 0, 0);
    q = __builtin_amdgcn_mfma_f32_16x16x32_bf16(T.a0, bh1[0], q, 0, 0, 0);
    p = __builtin_amdgcn_mfma_f32_16x16x32_bf16(T.a0, bl0[0], p, 0, 0, 0);
    q = __builtin_amdgcn_mfma_f32_16x16x32_bf16(T.a0, bl1[0], q, 0, 0, 0);
    p = __builtin_amdgcn_mfma_f32_16x16x32_bf16(T.a2, bh0[0], p, 0, 0, 0);
    q = __builtin_amdgcn_mfma_f32_16x16x32_bf16(T.a2, bh1[0], q, 0, 0, 0);
    p = __builtin_amdgcn_mfma_f32_16x16x32_bf16(T.a1, bh0[1], p, 0, 0, 0);
    q = __builtin_amdgcn_mfma_f32_16x16x32_bf16(T.a1, bh1[1], q, 0, 0, 0);
    p = __builtin_amdgcn_mfma_f32_16x16x32_bf16(T.a1, bl0[1], p, 0, 0, 0);
    q = __builtin_amdgcn_mfma_f32_16x16x32_bf16(T.a1, bl1[1], q, 0, 0, 0);
    p = __builtin_amdgcn_mfma_f32_16x16x32_bf16(T.a3, bh0[1], p, 0, 0, 0);
    q = __builtin_amdgcn_mfma_f32_16x16x32_bf16(T.a3, bh1[1], q, 0, 0, 0);

    const unsigned s4[4] = {T.sv.x, T.sv.y, T.sv.z, T.sv.w};
    #pragma unroll
    for (int r = 0; r < 4; ++r) {
        const unsigned sqb = s4[r] & ~31u, lb = s4[r] & 31u;   // shared by both i-groups
        float d0 = sqi0 + __uint_as_float(sqb) + p[r];
        c0[r] = (int)((__float_as_uint(d0) & ~31u) | lb);       // v_and_or_b32
        float d1 = sqi1 + __uint_as_float(sqb) + q[r];
        c1[r] = (int)((__float_as_uint(d1) & ~31u) | lb);
    }
}

// Output layout (f32, flat): [0..524287] encodings | [524288..532479] nbr entropy |
// [532480] cluster entropy | [532481] n_populated | [532482..540673] max_groups
//
// Workspace: slab u32[8192] @0 (bits(sq)&~31|label) | enc1 @32768 (2 MB, grouped frags of e)
//   enc2 @2129920 (2 MB, grouped frags of -2e). Ring offsets wrap mod 2 MB; all
//   tile reads stay inside enc2 (wrapped final refills re-read valid tiles, unused).

__global__ __launch_bounds__(256) void pre_kernel(
    const float* __restrict__ enc, const float* __restrict__ cat,
    unsigned int* __restrict__ slab,
    char* __restrict__ enc1, char* __restrict__ enc2,
    float* __restrict__ out_max, float* __restrict__ out_enc)
{
    const int gid = blockIdx.x * 256 + threadIdx.x;   // 1024 x 256 = 262144
    const int p = gid >> 5, pr = gid & 31;            // 32 threads/row, dims 2pr..2pr+1

    // single enc read serves passthrough copy and conversion (coalesced float2)
    float2 ev = ((const float2*)enc)[gid];
    ((float2*)out_enc)[gid] = ev;

    float s = ev.x * ev.x + ev.y * ev.y;
    #pragma unroll
    for (int m = 1; m < 32; m <<= 1) s += __shfl_xor(s, m, 32);   // row ssq

    // fragment-native address for dims d0 = 2pr, 2pr+1 (same 16B piece: d0 even)
    {
        const int g = p >> 4, c15p = p & 15;
        const int d0 = 2 * pr, kh = d0 >> 5, q = (d0 >> 3) & 3, e0 = d0 & 7;
        const int base = g * 4096 + kh * 1024 + (q * 16 + c15p) * 16 + e0 * 2;
        unsigned short ha = f2bf(ev.x), hb = f2bf(ev.y);
        unsigned short la = f2bf(ev.x - bf2f(ha)), lb = f2bf(ev.y - bf2f(hb));
        *(unsigned*)(enc1 + base)        = (unsigned)ha | ((unsigned)hb << 16);
        *(unsigned*)(enc1 + base + 2048) = (unsigned)la | ((unsigned)lb << 16);
        float y0 = -2.f * ev.x, y1 = -2.f * ev.y;
        unsigned short hc = f2bf(y0), hd = f2bf(y1);
        unsigned short lc = f2bf(y0 - bf2f(hc)), ld = f2bf(y1 - bf2f(hd));
        *(unsigned*)(enc2 + base)        = (unsigned)hc | ((unsigned)hd << 16);
        *(unsigned*)(enc2 + base + 2048) = (unsigned)lc | ((unsigned)ld << 16);
    }
    // categorical argmax across 32 lanes (first-max: ties -> min index; cat >= 0 so -1 sentinel safe)
    float cv = (pr < NC) ? cat[p * NC + pr] : -1.f;
    int ci = pr;
    #pragma unroll
    for (int m = 1; m < 32; m <<= 1) {
        float ov = __shfl_xor(cv, m, 32);
        int   oi = __shfl_xor(ci, m, 32);
        if (ov > cv || (ov == cv && oi < ci)) { cv = ov; ci = oi; }
    }
    if (pr == 0) {
        out_max[p] = cv;
        slab[p] = (__float_as_uint(s) & ~31u) | (unsigned)ci;  // sq trunc 2^-18 rel, harmless
    }
}

// Grid 256 x 512 threads (8 waves): one block per 32 i-rows, 1 block/CU.
// Wave wv owns j-groups g ≡ wv (mod 8): 64 tiles; pipeline pair p = tiles at
// wvoff + p*65536 (+32768), R6-verified 4-phase ping-pong + sched_barrier.
// NEW (R12): s_setprio(1) around each MFMA+pack region — no barriers in this
// loop, waves drift independently through load/MFMA/sort phases, so elevating
// the MFMA-phase wave tightens pipe interleave (the m191 regime).
__global__ __launch_bounds__(512) void main_kernel(
    const char* __restrict__ enc1, const char* __restrict__ enc2,
    const unsigned int* __restrict__ slab, const int* __restrict__ kptr,
    float* __restrict__ out_ent, float* __restrict__ out_glob)
{
    __shared__ int wl[8 * 32 * 17];   // 17408 B epilogue merge area (8 waves x 32 rows)
    __shared__ int cnt[32];

    const int tid  = threadIdx.x, bid = blockIdx.x;
    const int wv   = tid >> 6, lane = tid & 63;
    const int quad = (tid >> 4) & 3, c15 = tid & 15;
    const int rowbase = bid * RT;
    const int lane16 = lane * 16, quad4 = quad * 4;

    // i-fragments for BOTH i-groups (L1 broadcast across waves), hoisted
    short8 bh0[2], bl0[2], bh1[2], bl1[2];
    {
        const char* ib = enc1 + (size_t)bid * 8192 + lane16;
        bh0[0] = *(const short8*)(ib);
        bh0[1] = *(const short8*)(ib + 1024);
        bl0[0] = *(const short8*)(ib + 2048);
        bl0[1] = *(const short8*)(ib + 3072);
        bh1[0] = *(const short8*)(ib + 4096);
        bh1[1] = *(const short8*)(ib + 5120);
        bl1[0] = *(const short8*)(ib + 6144);
        bl1[1] = *(const short8*)(ib + 7168);
    }
    const float sqi0 = __uint_as_float(slab[rowbase + c15] & ~31u);
    const float sqi1 = __uint_as_float(slab[rowbase + 16 + c15] & ~31u);

    int ls0[KCAP], ls1[KCAP];   // per-thread sorted-ascending top-16 keys, per i-group
    #pragma unroll
    for (int q = 0; q < KCAP; ++q) { ls0[q] = SENT; ls1[q] = SENT; }

    const int wvoff = wv * 4096;

    TileR A0, A1, B0, B1;
    // prologue: pair 0 into A buffers
    tile_load(A0, enc2, slab, wvoff,          lane16, quad4);
    tile_load(A1, enc2, slab, wvoff + 32768,  lane16, quad4);

    #pragma unroll 1
    for (int p = 0; p < 32; p += 2) {
        int c0[16], c1[16];
        // phase 1: prefetch pair p+1 tile A -> B0; compute A0 vs both i-groups
        {
            const int o = (wvoff + (p + 1) * 65536) & JMASK;
            tile_load(B0, enc2, slab, o, lane16, quad4);
        }
        __builtin_amdgcn_sched_barrier(0);
        __builtin_amdgcn_s_setprio(1);
        tile_mfma2(A0, bh0, bl0, bh1, bl1, sqi0, sqi1, c0, c1);
        __builtin_amdgcn_s_setprio(0);
        // phase 2: prefetch pair p+1 tile B -> B1; compute A1
        {
            const int o = ((wvoff + (p + 1) * 65536) & JMASK) + 32768;
            tile_load(B1, enc2, slab, o, lane16, quad4);
        }
        __builtin_amdgcn_sched_barrier(0);
        __builtin_amdgcn_s_setprio(1);
        tile_mfma2(A1, bh0, bl0, bh1, bl1, sqi0, sqi1, c0 + 4, c1 + 4);
        __builtin_amdgcn_s_setprio(0);
        // phase 3: refill A0 with pair p+2 tile A; compute B0
        {
            const int o = (wvoff + (p + 2) * 65536) & JMASK;   // p=30 wraps to pair 0, unused
            tile_load(A0, enc2, slab, o, lane16, quad4);
        }
        __builtin_amdgcn_sched_barrier(0);
        __builtin_amdgcn_s_setprio(1);
        tile_mfma2(B0, bh0, bl0, bh1, bl1, sqi0, sqi1, c0 + 8, c1 + 8);
        __builtin_amdgcn_s_setprio(0);
        // phase 4: refill A1 with pair p+2 tile B; compute B1
        {
            const int o = ((wvoff + (p + 2) * 65536) & JMASK) + 32768;
            tile_load(A1, enc2, slab, o, lane16, quad4);
        }
        __builtin_amdgcn_sched_barrier(0);
        __builtin_amdgcn_s_setprio(1);
        tile_mfma2(B1, bh0, bl0, bh1, bl1, sqi0, sqi1, c0 + 12, c1 + 12);
        __builtin_amdgcn_s_setprio(0);
        // branchless selection on both 16-candidate batches (hides A-refill flight)
        oesort16(c0);
        bmerge16(ls0, c0);
        oesort16(c1);
        bmerge16(ls1, c1);
    }

    // ---- block 0: global cluster entropy from slab labels (block-uniform branch) ----
    if (bid == 0) {
        if (tid < 32) cnt[tid] = 0;
        __syncthreads();
        for (int i = tid; i < Bsz; i += 512) atomicAdd(&cnt[slab[i] & 31u], 1);
        __syncthreads();
        if (tid == 0) {
            float gent = 0.f, npop = 0.f;
            for (int i = 0; i < NC; ++i) {
                int g = cnt[i];
                if (g > 0) {
                    npop += 1.f;
                    float gb = (float)g / (float)Bsz;
                    gent -= gb * logf(gb + EPSf);
                }
            }
            out_glob[0] = gent;
            out_glob[1] = npop;
        }
        __syncthreads();
    }

    // ---- epilogue: merge 4 quads (shfl) per i-group, then 8 waves (LDS), per i-row ----
    bmerge16_shfl(ls0, 16);   // quad ^ 1
    bmerge16_shfl(ls0, 32);   // quad ^ 2 -> wave-level sorted top-16 (rows 0..15)
    bmerge16_shfl(ls1, 16);
    bmerge16_shfl(ls1, 32);   // rows 16..31
    if (quad == 0) {
        #pragma unroll
        for (int q = 0; q < KCAP; ++q) wl[(wv * 32 + c15) * 17 + q]      = ls0[q];
        #pragma unroll
        for (int q = 0; q < KCAP; ++q) wl[(wv * 32 + 16 + c15) * 17 + q] = ls1[q];
    }
    __syncthreads();
    if (wv < 2) {   // 128 threads: 32 rows x 4 subs, merge 8 wave-lists -> entropy
        const int row = tid >> 2, sub = tid & 3;   // row 0..31, sub-groups stay in-wave
        int A[16], Bv[16];
        #pragma unroll
        for (int i = 0; i < 16; ++i) A[i]  = wl[((2 * sub)     * 32 + row) * 17 + i];
        #pragma unroll
        for (int i = 0; i < 16; ++i) Bv[i] = wl[((2 * sub + 1) * 32 + row) * 17 + i];
        bmerge16(A, Bv);
        bmerge16_shfl(A, 1);   // sub ^ 1
        bmerge16_shfl(A, 2);   // sub ^ 2 -> row's global sorted top-16 in all subs

        int kk = kptr[0];
        if (kk > Bsz / 4) kk = Bsz / 4;
        if (kk > KCAP - 1) kk = KCAP - 1;

        int kth = A[15];
        #pragma unroll
        for (int q = 0; q < 16; ++q) if (q == kk) kth = A[q];
        int nn = 0;
        #pragma unroll
        for (int t = 0; t < 15; ++t) nn += (t < kk && A[t] < kth) ? 1 : 0;  // strict <, sorted prefix

        float inv = 1.f / (float)((nn > 0) ? nn : 1);
        float part = 0.f;
        #pragma unroll
        for (int a4 = 0; a4 < 4; ++a4) {
            int a = sub + 4 * a4;
            if (a < nn) {
                int la = A[a] & 31;
                int c = 0;
                #pragma unroll
                for (int b = 0; b < 15; ++b) c += (b < nn && (A[b] & 31) == la) ? 1 : 0;
                part -= inv * logf((float)c * inv + EPSf);
            }
        }
        part += __shfl_xor(part, 1);
        part += __shfl_xor(part, 2);
        if (sub == 0) out_ent[rowbase + row] = part;
    }
}

extern "C" void kernel_launch(void* const* d_in, const int* in_sizes, int n_in,
                              void* d_out, int out_size, void* d_ws, size_t ws_size,
                              hipStream_t stream)
{
    const float* enc  = (const float*)d_in[0];
    const float* cat  = (const float*)d_in[1];
    const int*   kptr = (const int*)d_in[2];
    float* out = (float*)d_out;

    unsigned int* slab = (unsigned int*)d_ws;
    char*         enc1 = (char*)d_ws + 32768;
    char*         enc2 = (char*)d_ws + 2129920;

    float* out_enc  = out;
    float* out_ent  = out + Bsz * Dd;                 // 524288
    float* out_glob = out + Bsz * Dd + Bsz;           // 532480 (entropy, n_populated)
    float* out_max  = out + Bsz * Dd + Bsz + 2;       // 532482

    pre_kernel<<<1024, 256, 0, stream>>>(enc, cat, slab, enc1, enc2, out_max, out_enc);
    main_kernel<<<Bsz / RT, 512, 0, stream>>>(enc1, enc2, slab, kptr, out_ent, out_glob);
}